// Round 8
// baseline (291.347 us; speedup 1.0000x reference)
//
#include <hip/hip_runtime.h>
#include <hip/hip_fp16.h>

#define N_NODES 100000
#define N_EDGES 1600000
#define IN_DIM 128
#define HIDDEN 16
#define OUT_DIM 40
#define QMAXF 255.0f

#define NB 512            // row buckets
#define RPB 196           // rows per bucket
#define NB_USED 511       // buckets actually populated (0..510)
#define BUCKET_CAP 4096   // mean fill 3136, 17 sigma headroom
#define TILE 1024         // edges per bin block (small => 21.5KB LDS, 7 blk/CU)
#define EPT 4             // edges/thread in bin path
#define NBLK_BIN ((N_EDGES + TILE - 1) / TILE)  // 1563
#define HALF_CAP 2560     // stage cap for 98-row half bucket (mean 1568, 25s)
#define GEMM1_BLOCKS 1537

// padded dq buffer: 4 k-blocks of 32 floats, block stride 34 floats
// -> read banks (2*kg+i)%32 distinct across the 4 sixteen-lane groups
#define DQ_STRIDE 34
#define DQ_LEN 136        // 4*34

typedef float vfloat4 __attribute__((ext_vector_type(4)));

__device__ __forceinline__ float qd_one(float x, float noise, float rmin,
                                        float rscale, float inv) {
    float q = rintf((x - rmin) * rscale + noise - 0.5f);
    q = fminf(fmaxf(q, 0.0f), QMAXF);
    return q * inv + rmin;
}

// ---------------- merged: edge binning + layer1 qd-GEMM ---------------------
// Binning depends only on edges; gemm1 only on feat/noise -> run them in ONE
// dispatch, interleaved across blockIdx so both kinds are co-resident and the
// bin scatter latency hides under gemm1's streaming compute.
// cursor[] holds per-bucket COUNTS (zeroed via hipMemsetAsync); global base is
// b*BUCKET_CAP + old_count.

struct BinLds {
    int hist[NB];
    int psum[256];
    int lofs[NB];
    int lcur[NB];
    int gbase[NB];
    long long stage[TILE];
    int dsti[TILE];
};  // 21.5 KB
union K1Lds {
    BinLds b;
    float dqbuf[4][DQ_LEN];  // per-wave padded slice (gemm1 path)
};

__global__ __launch_bounds__(256, 4) void k_bin_gemm1(
    const int* __restrict__ row, const int* __restrict__ col,
    const float* __restrict__ vals, int* __restrict__ cursor,
    long long* __restrict__ es, const float* __restrict__ feat,
    const float* __restrict__ noise, const float* __restrict__ W1,
    __half* __restrict__ y) {
    __shared__ K1Lds u;
    const int tid = threadIdx.x;

    // interleaved role assignment: even ids -> bin, odd -> gemm1, tail -> bin
    const int bidx = blockIdx.x;
    bool isBin;
    int id;
    if (bidx < 2 * GEMM1_BLOCKS) {
        isBin = !(bidx & 1);
        id = bidx >> 1;
    } else {
        isBin = true;
        id = bidx - GEMM1_BLOCKS;
    }

    if (isBin) {
        // ---------- bin TILE edges into row buckets -------------------------
        for (int i = tid; i < NB; i += 256) u.b.hist[i] = 0;
        __syncthreads();

        int bk[EPT];
        long long ev[EPT];
        const int e0 = id * TILE;
#pragma unroll
        for (int k = 0; k < EPT; ++k) {
            const int e = e0 + k * 256 + tid;
            if (e < N_EDGES) {
                const int r = __builtin_nontemporal_load(row + e);
                const int cc = __builtin_nontemporal_load(col + e);
                const float vv = __builtin_nontemporal_load(vals + e);
                const int b = r / RPB;
                bk[k] = b;
                const unsigned lo = (unsigned)(cc | ((r - b * RPB) << 17));
                ev[k] = (long long)(
                    ((unsigned long long)__float_as_uint(vv) << 32) | lo);
                atomicAdd(&u.b.hist[b], 1);
            } else {
                bk[k] = -1;
            }
        }
        __syncthreads();

        const int h0 = u.b.hist[2 * tid], h1 = u.b.hist[2 * tid + 1];
        u.b.psum[tid] = h0 + h1;
        __syncthreads();
        for (int off = 1; off < 256; off <<= 1) {
            int x = (tid >= off) ? u.b.psum[tid - off] : 0;
            __syncthreads();
            u.b.psum[tid] += x;
            __syncthreads();
        }
        const int excl = (tid == 0) ? 0 : u.b.psum[tid - 1];
        u.b.lofs[2 * tid] = excl;
        u.b.lofs[2 * tid + 1] = excl + h0;
        u.b.lcur[2 * tid] = excl;
        u.b.lcur[2 * tid + 1] = excl + h0;
        if (h0)
            u.b.gbase[2 * tid] =
                2 * tid * BUCKET_CAP + atomicAdd(&cursor[2 * tid], h0);
        if (h1)
            u.b.gbase[2 * tid + 1] = (2 * tid + 1) * BUCKET_CAP +
                                     atomicAdd(&cursor[2 * tid + 1], h1);
        __syncthreads();

#pragma unroll
        for (int k = 0; k < EPT; ++k) {
            if (bk[k] >= 0) {
                const int b = bk[k];
                const int lp = atomicAdd(&u.b.lcur[b], 1);
                u.b.stage[lp] = ev[k];
                u.b.dsti[lp] = u.b.gbase[b] + (lp - u.b.lofs[b]);
            }
        }
        __syncthreads();

        const int S = u.b.psum[255];
        for (int i = tid; i < S; i += 256)
            __builtin_nontemporal_store(u.b.stage[i], es + u.b.dsti[i]);
    } else {
        // ---------- layer-1 quant-dequant + GEMM (128 -> 16) ----------------
        // Wave-private dqbuf slice: no block barriers; compiler orders the
        // same-wave ds_write -> ds_read dependency.  [R4-proven form]
        const int vb = id;
        const int lane = tid & 63;
        const int wv = tid >> 6;
        const int col_ = lane & 15;
        const int kg = lane >> 4;

        float w1r[32];
#pragma unroll
        for (int i = 0; i < 32; ++i)
            w1r[i] = W1[(kg * 32 + i) * HIDDEN + col_];

        float* const myslice = u.dqbuf[wv];
        float2* const wptr =
            (float2*)&myslice[kg * DQ_STRIDE + (lane & 15) * 2];
        const float* const dqk = &myslice[kg * DQ_STRIDE];

        const int ngroups = N_NODES / 4;  // 25000
        for (int g = vb; g < ngroups; g += GEMM1_BLOCKS) {
            const int node = g * 4 + wv;
            const unsigned long long xr = __builtin_nontemporal_load(
                (const unsigned long long*)(feat + (size_t)node * IN_DIM) +
                lane);
            const unsigned long long nr = __builtin_nontemporal_load(
                (const unsigned long long*)(noise + (size_t)node * IN_DIM) +
                lane);
            const float xx = __uint_as_float((unsigned)xr);
            const float xy = __uint_as_float((unsigned)(xr >> 32));
            const float nx = __uint_as_float((unsigned)nr);
            const float ny = __uint_as_float((unsigned)(nr >> 32));
            float m = fminf(xx, xy), M = fmaxf(xx, xy);
#pragma unroll
            for (int off = 1; off < 64; off <<= 1) {
                m = fminf(m, __shfl_xor(m, off));
                M = fmaxf(M, __shfl_xor(M, off));
            }
            const float rscale = QMAXF / (M - m);
            const float inv = (M - m) / QMAXF;
            float2 dq;
            dq.x = qd_one(xx, nx, m, rscale, inv);
            dq.y = qd_one(xy, ny, m, rscale, inv);
            *wptr = dq;
            float acc = 0.0f;
#pragma unroll
            for (int i = 0; i < 32; ++i) acc += dqk[i] * w1r[i];
            acc += __shfl_xor(acc, 16);
            acc += __shfl_xor(acc, 32);
            if (lane < 16) y[(size_t)node * HIDDEN + lane] = __float2half(acc);
        }
    }
}

// ---------------- standalone bucket sort (direct global scatter) ------------
// 3KB LDS, all 511 blocks co-resident; ~10-15us.  [R4-proven form]

__global__ __launch_bounds__(256, 4) void k_sort(
    const int* __restrict__ cursor, long long* __restrict__ es,
    int* __restrict__ rowEnd) {
    __shared__ int hist[256];
    __shared__ int psum[256];
    __shared__ int cur[256];

    const int b = blockIdx.x;
    const int tid = threadIdx.x;
    const int start = b * BUCKET_CAP;
    const int cnt = cursor[b];

    hist[tid] = 0;
    __syncthreads();

    long long ev[16];
#pragma unroll
    for (int k = 0; k < 16; ++k) {
        const int i = k * 256 + tid;
        if (i < cnt) {
            ev[k] = es[start + i];
            atomicAdd(&hist[(int)(((unsigned)ev[k]) >> 17)], 1);
        }
    }
    __syncthreads();  // drains vmcnt: all es reads done before scatter

    psum[tid] = hist[tid];
    __syncthreads();
    for (int off = 1; off < 256; off <<= 1) {
        int x = (tid >= off) ? psum[tid - off] : 0;
        __syncthreads();
        psum[tid] += x;
        __syncthreads();
    }
    if (tid < RPB) rowEnd[b * RPB + tid] = start + psum[tid];
    cur[tid] = psum[tid] - hist[tid];
    __syncthreads();

#pragma unroll
    for (int k = 0; k < 16; ++k) {
        const int i = k * 256 + tid;
        if (i < cnt) {
            const int r = (int)(((unsigned)ev[k]) >> 17);
            const int pos = atomicAdd(&cur[r], 1);
            es[start + pos] = ev[k];
        }
    }
}

// ---------------- SpMM with fused per-layer epilogue ------------------------
// LAYER==1: spmm -> relu -> qd(noise2) -> @W2 -> half yout
// LAYER==2: spmm -> relu -> qd(noise3) -> half yout
// LAYER==3: spmm -> @W3 -> float out
// [R4-proven form: LDS edge stage + 4-wide unrolled gather]

template <int LAYER>
__global__ __launch_bounds__(256, 4) void k_spmm_f(
    const int* __restrict__ rowEnd, const long long* __restrict__ es,
    const __half* __restrict__ y, const float* __restrict__ noise,
    const float* __restrict__ W, __half* __restrict__ yout,
    float* __restrict__ out) {
    __shared__ long long stage[HALF_CAP];  // 20.5 KB
    __shared__ int rp[100];
    __shared__ int sh_se[2];
    __shared__ float wsh[LAYER == 1 ? (HIDDEN * HIDDEN)
                                    : (LAYER == 3 ? (HIDDEN * OUT_DIM) : 4)];

    const int b = blockIdx.x >> 1;
    const int hbk = blockIdx.x & 1;
    const int tid = threadIdx.x;
    const int r0 = hbk * 98;
    const int gb = b * RPB;
    const int bstart = b * BUCKET_CAP;

    if (tid == 0) {
        sh_se[0] = (r0 == 0) ? bstart : rowEnd[gb + r0 - 1];
        sh_se[1] = rowEnd[gb + r0 + 97];
    }
    if (tid < 99) rp[tid + 1] = rowEnd[gb + r0 + tid];
    if (LAYER == 1) {
        wsh[tid] = W[tid];  // 256 weights, 256 threads
    }
    if (LAYER == 3) {
        for (int i = tid; i < HIDDEN * OUT_DIM; i += 256) wsh[i] = W[i];
    }
    __syncthreads();
    const int estart = sh_se[0];
    const int cnt = sh_se[1] - estart;
    if (tid == 0) rp[0] = estart;
    __syncthreads();

    for (int i = tid; i < cnt; i += 256)
        stage[i] = __builtin_nontemporal_load(es + estart + i);
    __syncthreads();

    if (tid >= 196) return;
    const int lr = tid >> 1;  // 0..97 local row
    const int h = tid & 1;    // half-row: halfs [h*8, h*8+8)
    const int grow = gb + r0 + lr;
    int j = rp[lr] - estart;
    const int je = rp[lr + 1] - estart;

    float acc[8];
#pragma unroll
    for (int i = 0; i < 8; ++i) acc[i] = 0.0f;

    for (; j + 4 <= je; j += 4) {
        const long long e0 = stage[j], e1 = stage[j + 1];
        const long long e2 = stage[j + 2], e3 = stage[j + 3];
        const uint4 a0 = *(const uint4*)(y + (size_t)(((unsigned)e0) & 0x1FFFF) * HIDDEN + h * 8);
        const uint4 a1 = *(const uint4*)(y + (size_t)(((unsigned)e1) & 0x1FFFF) * HIDDEN + h * 8);
        const uint4 a2 = *(const uint4*)(y + (size_t)(((unsigned)e2) & 0x1FFFF) * HIDDEN + h * 8);
        const uint4 a3 = *(const uint4*)(y + (size_t)(((unsigned)e3) & 0x1FFFF) * HIDDEN + h * 8);
        const float v0 = __uint_as_float((unsigned)((unsigned long long)e0 >> 32));
        const float v1 = __uint_as_float((unsigned)((unsigned long long)e1 >> 32));
        const float v2 = __uint_as_float((unsigned)((unsigned long long)e2 >> 32));
        const float v3 = __uint_as_float((unsigned)((unsigned long long)e3 >> 32));
        const unsigned* p0 = (const unsigned*)&a0;
        const unsigned* p1 = (const unsigned*)&a1;
        const unsigned* p2 = (const unsigned*)&a2;
        const unsigned* p3 = (const unsigned*)&a3;
#pragma unroll
        for (int q = 0; q < 4; ++q) {
            float2 f;
            f = __half22float2(*(const __half2*)&p0[q]);
            acc[2 * q] += v0 * f.x; acc[2 * q + 1] += v0 * f.y;
            f = __half22float2(*(const __half2*)&p1[q]);
            acc[2 * q] += v1 * f.x; acc[2 * q + 1] += v1 * f.y;
            f = __half22float2(*(const __half2*)&p2[q]);
            acc[2 * q] += v2 * f.x; acc[2 * q + 1] += v2 * f.y;
            f = __half22float2(*(const __half2*)&p3[q]);
            acc[2 * q] += v3 * f.x; acc[2 * q + 1] += v3 * f.y;
        }
    }
    for (; j < je; ++j) {
        const long long e = stage[j];
        const float v = __uint_as_float((unsigned)((unsigned long long)e >> 32));
        const uint4 a = *(const uint4*)(y + (size_t)(((unsigned)e) & 0x1FFFF) * HIDDEN + h * 8);
        const unsigned* p = (const unsigned*)&a;
#pragma unroll
        for (int q = 0; q < 4; ++q) {
            const float2 f = __half22float2(*(const __half2*)&p[q]);
            acc[2 * q] += v * f.x;
            acc[2 * q + 1] += v * f.y;
        }
    }

    if (grow >= N_NODES) return;

    if (LAYER == 1 || LAYER == 2) {
        // relu + row min/max (exchange with partner half)
#pragma unroll
        for (int i = 0; i < 8; ++i) acc[i] = fmaxf(acc[i], 0.0f);
        float m = acc[0], M = acc[0];
#pragma unroll
        for (int i = 1; i < 8; ++i) {
            m = fminf(m, acc[i]);
            M = fmaxf(M, acc[i]);
        }
        m = fminf(m, __shfl_xor(m, 1));
        M = fmaxf(M, __shfl_xor(M, 1));
        const float rscale = QMAXF / (M - m);
        const float inv = (M - m) / QMAXF;
        float nz[8];
        {
            const float4* nr =
                (const float4*)(noise + (size_t)grow * HIDDEN + h * 8);
            ((float4*)nz)[0] = nr[0];
            ((float4*)nz)[1] = nr[1];
        }
        float dq[8];
#pragma unroll
        for (int i = 0; i < 8; ++i)
            dq[i] = qd_one(acc[i], nz[i], m, rscale, inv);

        if (LAYER == 2) {
            __half hb8[8];
#pragma unroll
            for (int i = 0; i < 8; ++i) hb8[i] = __float2half(dq[i]);
            *(float4*)(yout + (size_t)grow * HIDDEN + h * 8) = *(float4*)hb8;
        } else {
            // @W2: my k-rows = [h*8, h*8+8), partner's via shuffle; my output
            // cols = [h*8, h*8+8).
            float dp[8];
#pragma unroll
            for (int i = 0; i < 8; ++i) dp[i] = __shfl_xor(dq[i], 1);
            const int kb = h * 8;
            const int pb = 8 - kb;
            const float* wmy = wsh + kb * HIDDEN + kb;
            const float* wpr = wsh + pb * HIDDEN + kb;
            float o[8];
#pragma unroll
            for (int jj = 0; jj < 8; ++jj) o[jj] = 0.0f;
#pragma unroll
            for (int i = 0; i < 8; ++i) {
#pragma unroll
                for (int jj = 0; jj < 8; ++jj) {
                    o[jj] += dq[i] * wmy[i * HIDDEN + jj];
                    o[jj] += dp[i] * wpr[i * HIDDEN + jj];
                }
            }
            __half hb8[8];
#pragma unroll
            for (int jj = 0; jj < 8; ++jj) hb8[jj] = __float2half(o[jj]);
            *(float4*)(yout + (size_t)grow * HIDDEN + kb) = *(float4*)hb8;
        }
    } else {
        // LAYER 3: @W3 (16x40), my output cols = [h*20, h*20+20)
        float ap[8];
#pragma unroll
        for (int i = 0; i < 8; ++i) ap[i] = __shfl_xor(acc[i], 1);
        const int kb = h * 8;
        const int pb = 8 - kb;
        const int ob = h * 20;
        const float* wmy = wsh + kb * OUT_DIM + ob;
        const float* wpr = wsh + pb * OUT_DIM + ob;
        float o[20];
#pragma unroll
        for (int jj = 0; jj < 20; ++jj) o[jj] = 0.0f;
#pragma unroll
        for (int i = 0; i < 8; ++i) {
#pragma unroll
            for (int jj = 0; jj < 20; ++jj) {
                o[jj] += acc[i] * wmy[i * OUT_DIM + jj];
                o[jj] += ap[i] * wpr[i * OUT_DIM + jj];
            }
        }
        float* orow = out + (size_t)grow * OUT_DIM + ob;
#pragma unroll
        for (int j4 = 0; j4 < 5; ++j4)
            __builtin_nontemporal_store(((const vfloat4*)o)[j4],
                                        (vfloat4*)orow + j4);
    }
}

extern "C" void kernel_launch(void* const* d_in, const int* in_sizes, int n_in,
                              void* d_out, int out_size, void* d_ws,
                              size_t ws_size, hipStream_t stream) {
    const float* feat = (const float*)d_in[0];
    const int* row = (const int*)d_in[1];
    const int* col = (const int*)d_in[2];
    const float* vals = (const float*)d_in[3];
    const float* W1 = (const float*)d_in[4];
    const float* W2 = (const float*)d_in[5];
    const float* W3 = (const float*)d_in[6];
    const float* n1 = (const float*)d_in[7];
    const float* n2 = (const float*)d_in[8];
    const float* n3 = (const float*)d_in[9];
    float* out = (float*)d_out;

    __half* yh1 = (__half*)d_ws;                            // 3.2 MB
    __half* yh2 = yh1 + (size_t)N_NODES * HIDDEN;           // 3.2 MB
    int* cursor = (int*)(yh2 + (size_t)N_NODES * HIDDEN);   // NB ints
    int* rowEnd = cursor + NB;                              // NB*RPB ints
    long long* es = (long long*)(rowEnd + NB * RPB);        // 16.8 MB

    // --- [bin || layer-1 qd-GEMM] in one dispatch, then cheap standalone sort
    hipMemsetAsync(cursor, 0, NB * sizeof(int), stream);
    k_bin_gemm1<<<NBLK_BIN + GEMM1_BLOCKS, 256, 0, stream>>>(
        row, col, vals, cursor, es, feat, n1, W1, yh1);
    k_sort<<<NB_USED, 256, 0, stream>>>(cursor, es, rowEnd);

    // Layer 1 spmm + (relu, qd(noise2), @W2) fused epilogue
    k_spmm_f<1><<<NB_USED * 2, 256, 0, stream>>>(rowEnd, es, yh1, n2, W2, yh2,
                                                 nullptr);
    // Layer 2 spmm + (relu, qd(noise3)) fused epilogue
    k_spmm_f<2><<<NB_USED * 2, 256, 0, stream>>>(rowEnd, es, yh2, n3, nullptr,
                                                 yh1, nullptr);
    // Layer 3 spmm + @W3 fused epilogue
    k_spmm_f<3><<<NB_USED * 2, 256, 0, stream>>>(rowEnd, es, yh1, nullptr, W3,
                                                 nullptr, out);
}

// Round 9
// 285.801 us; speedup vs baseline: 1.0194x; 1.0194x over previous
//
#include <hip/hip_runtime.h>
#include <hip/hip_fp16.h>

#define N_NODES 100000
#define N_EDGES 1600000
#define IN_DIM 128
#define HIDDEN 16
#define OUT_DIM 40
#define QMAXF 255.0f

#define NB 512            // row buckets
#define RPB 196           // rows per bucket
#define NB_USED 511       // buckets actually populated (0..510)
#define BUCKET_CAP 4096   // mean fill 3136, 17 sigma headroom
#define TILE 2048         // edges per bin block: 33KB LDS, 782 blocks ~3/CU
#define EPT 8             // edges/thread in k_bin (TILE/256)
#define NBLK_BIN ((N_EDGES + TILE - 1) / TILE)  // 782
#define HALF_CAP 2560     // stage cap for 98-row half bucket (mean 1568, 25s)
#define GEMM1_BLOCKS 1537 // 511 + 1537 = 2048 = one full scheduling wave @8/CU

// padded dq buffer: 4 k-blocks of 32 floats, block stride 34 floats
// -> read banks (2*kg+i)%32 distinct across the 4 sixteen-lane groups
#define DQ_STRIDE 34
#define DQ_LEN 136        // 4*34

typedef float vfloat4 __attribute__((ext_vector_type(4)));

__device__ __forceinline__ float qd_one(float x, float noise, float rmin,
                                        float rscale, float inv) {
    float q = rintf((x - rmin) * rscale + noise - 0.5f);
    q = fminf(fmaxf(q, 0.0f), QMAXF);
    return q * inv + rmin;
}

// ---------------- edge binning (once) ---------------------------------------
// cursor[] holds per-bucket COUNTS (zeroed via hipMemsetAsync); global base is
// b*BUCKET_CAP + old_count. TILE=2048: 782 blocks (~3/CU co-resident, 12
// waves/CU latency hiding) while keeping ~4-edge (32B) scatter runs. R8
// showed TILE=1024 breaks scatter coalescing; R4's 4096 left 1.5 blocks/CU.

__global__ __launch_bounds__(256) void k_bin(
    const int* __restrict__ row, const int* __restrict__ col,
    const float* __restrict__ vals, int* __restrict__ cursor,
    long long* __restrict__ es) {
    __shared__ int hist[NB];
    __shared__ int psum[256];
    __shared__ int lofs[NB];
    __shared__ int lcur[NB];
    __shared__ int gbase[NB];
    __shared__ long long stage[TILE];
    __shared__ int dsti[TILE];

    const int tid = threadIdx.x;
    for (int i = tid; i < NB; i += 256) hist[i] = 0;
    __syncthreads();

    int bk[EPT];
    long long ev[EPT];
    const int e0 = blockIdx.x * TILE;
#pragma unroll
    for (int k = 0; k < EPT; ++k) {
        const int e = e0 + k * 256 + tid;
        if (e < N_EDGES) {
            const int r = __builtin_nontemporal_load(row + e);
            const int cc = __builtin_nontemporal_load(col + e);
            const float vv = __builtin_nontemporal_load(vals + e);
            const int b = r / RPB;
            bk[k] = b;
            const unsigned lo = (unsigned)(cc | ((r - b * RPB) << 17));
            ev[k] = (long long)(((unsigned long long)__float_as_uint(vv) << 32) |
                                lo);
            atomicAdd(&hist[b], 1);
        } else {
            bk[k] = -1;
        }
    }
    __syncthreads();

    const int h0 = hist[2 * tid], h1 = hist[2 * tid + 1];
    psum[tid] = h0 + h1;
    __syncthreads();
    for (int off = 1; off < 256; off <<= 1) {
        int x = (tid >= off) ? psum[tid - off] : 0;
        __syncthreads();
        psum[tid] += x;
        __syncthreads();
    }
    const int excl = (tid == 0) ? 0 : psum[tid - 1];
    lofs[2 * tid] = excl;
    lofs[2 * tid + 1] = excl + h0;
    lcur[2 * tid] = excl;
    lcur[2 * tid + 1] = excl + h0;
    if (h0)
        gbase[2 * tid] = 2 * tid * BUCKET_CAP + atomicAdd(&cursor[2 * tid], h0);
    if (h1)
        gbase[2 * tid + 1] =
            (2 * tid + 1) * BUCKET_CAP + atomicAdd(&cursor[2 * tid + 1], h1);
    __syncthreads();

#pragma unroll
    for (int k = 0; k < EPT; ++k) {
        if (bk[k] >= 0) {
            const int b = bk[k];
            const int lp = atomicAdd(&lcur[b], 1);
            stage[lp] = ev[k];
            dsti[lp] = gbase[b] + (lp - lofs[b]);
        }
    }
    __syncthreads();

    const int S = psum[255];
    for (int i = tid; i < S; i += 256)
        __builtin_nontemporal_store(stage[i], es + dsti[i]);
}

// ---------------- merged: bucket sort (blocks 0..510) + layer1 qd-GEMM ------
// Sort is edge-data-dependent only; gemm1 is feature-dependent only.
// Sort scatters DIRECTLY to global (no 32KB LDS stage) so the LDS union is
// ~3KB -> 8 blocks/CU; gemm1 path is barrier-free (each wave owns its dqbuf
// slice) with a bank-conflict-free padded layout.  [R4-proven form]

struct SortLds {
    int hist[256];
    int psum[256];
    int cur[256];
};
union K1Lds {
    SortLds s;
    float dqbuf[4][DQ_LEN];  // per-wave padded slice
};

__global__ __launch_bounds__(256, 4) void k_sort_gemm1(
    const int* __restrict__ cursor, long long* __restrict__ es,
    int* __restrict__ rowEnd, const float* __restrict__ feat,
    const float* __restrict__ noise, const float* __restrict__ W1,
    __half* __restrict__ y) {
    __shared__ K1Lds u;
    const int tid = threadIdx.x;

    if (blockIdx.x < NB_USED) {
        // ---------- in-register counting sort by row within this bucket -----
        const int b = blockIdx.x;
        const int start = b * BUCKET_CAP;
        const int cnt = cursor[b];

        u.s.hist[tid] = 0;
        __syncthreads();

        long long ev[16];
#pragma unroll
        for (int k = 0; k < 16; ++k) {
            const int i = k * 256 + tid;
            if (i < cnt) {
                ev[k] = es[start + i];
                atomicAdd(&u.s.hist[(int)(((unsigned)ev[k]) >> 17)], 1);
            }
        }
        __syncthreads();  // drains vmcnt: all es reads done before scatter

        u.s.psum[tid] = u.s.hist[tid];
        __syncthreads();
        for (int off = 1; off < 256; off <<= 1) {
            int x = (tid >= off) ? u.s.psum[tid - off] : 0;
            __syncthreads();
            u.s.psum[tid] += x;
            __syncthreads();
        }
        if (tid < RPB) rowEnd[b * RPB + tid] = start + u.s.psum[tid];
        u.s.cur[tid] = u.s.psum[tid] - u.s.hist[tid];
        __syncthreads();

#pragma unroll
        for (int k = 0; k < 16; ++k) {
            const int i = k * 256 + tid;
            if (i < cnt) {
                const int r = (int)(((unsigned)ev[k]) >> 17);
                const int pos = atomicAdd(&u.s.cur[r], 1);
                es[start + pos] = ev[k];
            }
        }
    } else {
        // ---------- layer-1 quant-dequant + GEMM (128 -> 16) ----------------
        // Wave-private dqbuf slice: no block barriers; compiler orders the
        // same-wave ds_write -> ds_read dependency.
        const int vb = blockIdx.x - NB_USED;
        const int lane = tid & 63;
        const int wv = tid >> 6;
        const int col = lane & 15;
        const int kg = lane >> 4;

        float w1r[32];
#pragma unroll
        for (int i = 0; i < 32; ++i) w1r[i] = W1[(kg * 32 + i) * HIDDEN + col];

        float* const myslice = u.dqbuf[wv];
        float2* const wptr =
            (float2*)&myslice[kg * DQ_STRIDE + (lane & 15) * 2];
        const float* const dqk = &myslice[kg * DQ_STRIDE];

        const int ngroups = N_NODES / 4;  // 25000
        for (int g = vb; g < ngroups; g += GEMM1_BLOCKS) {
            const int node = g * 4 + wv;
            const unsigned long long xr = __builtin_nontemporal_load(
                (const unsigned long long*)(feat + (size_t)node * IN_DIM) +
                lane);
            const unsigned long long nr = __builtin_nontemporal_load(
                (const unsigned long long*)(noise + (size_t)node * IN_DIM) +
                lane);
            const float xx = __uint_as_float((unsigned)xr);
            const float xy = __uint_as_float((unsigned)(xr >> 32));
            const float nx = __uint_as_float((unsigned)nr);
            const float ny = __uint_as_float((unsigned)(nr >> 32));
            float m = fminf(xx, xy), M = fmaxf(xx, xy);
#pragma unroll
            for (int off = 1; off < 64; off <<= 1) {
                m = fminf(m, __shfl_xor(m, off));
                M = fmaxf(M, __shfl_xor(M, off));
            }
            const float rscale = QMAXF / (M - m);
            const float inv = (M - m) / QMAXF;
            float2 dq;
            dq.x = qd_one(xx, nx, m, rscale, inv);
            dq.y = qd_one(xy, ny, m, rscale, inv);
            *wptr = dq;
            float acc = 0.0f;
#pragma unroll
            for (int i = 0; i < 32; ++i) acc += dqk[i] * w1r[i];
            acc += __shfl_xor(acc, 16);
            acc += __shfl_xor(acc, 32);
            if (lane < 16) y[(size_t)node * HIDDEN + lane] = __float2half(acc);
        }
    }
}

// ---------------- SpMM with fused per-layer epilogue ------------------------
// LAYER==1: spmm -> relu -> qd(noise2) -> @W2 -> half yout
// LAYER==2: spmm -> relu -> qd(noise3) -> half yout
// LAYER==3: spmm -> @W3 -> float out
// [R4-proven form: LDS edge stage + 4-wide unrolled gather]

template <int LAYER>
__global__ __launch_bounds__(256, 4) void k_spmm_f(
    const int* __restrict__ rowEnd, const long long* __restrict__ es,
    const __half* __restrict__ y, const float* __restrict__ noise,
    const float* __restrict__ W, __half* __restrict__ yout,
    float* __restrict__ out) {
    __shared__ long long stage[HALF_CAP];  // 20.5 KB
    __shared__ int rp[100];
    __shared__ int sh_se[2];
    __shared__ float wsh[LAYER == 1 ? (HIDDEN * HIDDEN)
                                    : (LAYER == 3 ? (HIDDEN * OUT_DIM) : 4)];

    const int b = blockIdx.x >> 1;
    const int hbk = blockIdx.x & 1;
    const int tid = threadIdx.x;
    const int r0 = hbk * 98;
    const int gb = b * RPB;
    const int bstart = b * BUCKET_CAP;

    if (tid == 0) {
        sh_se[0] = (r0 == 0) ? bstart : rowEnd[gb + r0 - 1];
        sh_se[1] = rowEnd[gb + r0 + 97];
    }
    if (tid < 99) rp[tid + 1] = rowEnd[gb + r0 + tid];
    if (LAYER == 1) {
        wsh[tid] = W[tid];  // 256 weights, 256 threads
    }
    if (LAYER == 3) {
        for (int i = tid; i < HIDDEN * OUT_DIM; i += 256) wsh[i] = W[i];
    }
    __syncthreads();
    const int estart = sh_se[0];
    const int cnt = sh_se[1] - estart;
    if (tid == 0) rp[0] = estart;
    __syncthreads();

    for (int i = tid; i < cnt; i += 256)
        stage[i] = __builtin_nontemporal_load(es + estart + i);
    __syncthreads();

    if (tid >= 196) return;
    const int lr = tid >> 1;  // 0..97 local row
    const int h = tid & 1;    // half-row: halfs [h*8, h*8+8)
    const int grow = gb + r0 + lr;
    int j = rp[lr] - estart;
    const int je = rp[lr + 1] - estart;

    float acc[8];
#pragma unroll
    for (int i = 0; i < 8; ++i) acc[i] = 0.0f;

    for (; j + 4 <= je; j += 4) {
        const long long e0 = stage[j], e1 = stage[j + 1];
        const long long e2 = stage[j + 2], e3 = stage[j + 3];
        const uint4 a0 = *(const uint4*)(y + (size_t)(((unsigned)e0) & 0x1FFFF) * HIDDEN + h * 8);
        const uint4 a1 = *(const uint4*)(y + (size_t)(((unsigned)e1) & 0x1FFFF) * HIDDEN + h * 8);
        const uint4 a2 = *(const uint4*)(y + (size_t)(((unsigned)e2) & 0x1FFFF) * HIDDEN + h * 8);
        const uint4 a3 = *(const uint4*)(y + (size_t)(((unsigned)e3) & 0x1FFFF) * HIDDEN + h * 8);
        const float v0 = __uint_as_float((unsigned)((unsigned long long)e0 >> 32));
        const float v1 = __uint_as_float((unsigned)((unsigned long long)e1 >> 32));
        const float v2 = __uint_as_float((unsigned)((unsigned long long)e2 >> 32));
        const float v3 = __uint_as_float((unsigned)((unsigned long long)e3 >> 32));
        const unsigned* p0 = (const unsigned*)&a0;
        const unsigned* p1 = (const unsigned*)&a1;
        const unsigned* p2 = (const unsigned*)&a2;
        const unsigned* p3 = (const unsigned*)&a3;
#pragma unroll
        for (int q = 0; q < 4; ++q) {
            float2 f;
            f = __half22float2(*(const __half2*)&p0[q]);
            acc[2 * q] += v0 * f.x; acc[2 * q + 1] += v0 * f.y;
            f = __half22float2(*(const __half2*)&p1[q]);
            acc[2 * q] += v1 * f.x; acc[2 * q + 1] += v1 * f.y;
            f = __half22float2(*(const __half2*)&p2[q]);
            acc[2 * q] += v2 * f.x; acc[2 * q + 1] += v2 * f.y;
            f = __half22float2(*(const __half2*)&p3[q]);
            acc[2 * q] += v3 * f.x; acc[2 * q + 1] += v3 * f.y;
        }
    }
    for (; j < je; ++j) {
        const long long e = stage[j];
        const float v = __uint_as_float((unsigned)((unsigned long long)e >> 32));
        const uint4 a = *(const uint4*)(y + (size_t)(((unsigned)e) & 0x1FFFF) * HIDDEN + h * 8);
        const unsigned* p = (const unsigned*)&a;
#pragma unroll
        for (int q = 0; q < 4; ++q) {
            const float2 f = __half22float2(*(const __half2*)&p[q]);
            acc[2 * q] += v * f.x;
            acc[2 * q + 1] += v * f.y;
        }
    }

    if (grow >= N_NODES) return;

    if (LAYER == 1 || LAYER == 2) {
        // relu + row min/max (exchange with partner half)
#pragma unroll
        for (int i = 0; i < 8; ++i) acc[i] = fmaxf(acc[i], 0.0f);
        float m = acc[0], M = acc[0];
#pragma unroll
        for (int i = 1; i < 8; ++i) {
            m = fminf(m, acc[i]);
            M = fmaxf(M, acc[i]);
        }
        m = fminf(m, __shfl_xor(m, 1));
        M = fmaxf(M, __shfl_xor(M, 1));
        const float rscale = QMAXF / (M - m);
        const float inv = (M - m) / QMAXF;
        float nz[8];
        {
            const float4* nr =
                (const float4*)(noise + (size_t)grow * HIDDEN + h * 8);
            ((float4*)nz)[0] = nr[0];
            ((float4*)nz)[1] = nr[1];
        }
        float dq[8];
#pragma unroll
        for (int i = 0; i < 8; ++i)
            dq[i] = qd_one(acc[i], nz[i], m, rscale, inv);

        if (LAYER == 2) {
            __half hb8[8];
#pragma unroll
            for (int i = 0; i < 8; ++i) hb8[i] = __float2half(dq[i]);
            *(float4*)(yout + (size_t)grow * HIDDEN + h * 8) = *(float4*)hb8;
        } else {
            // @W2: my k-rows = [h*8, h*8+8), partner's via shuffle; my output
            // cols = [h*8, h*8+8).
            float dp[8];
#pragma unroll
            for (int i = 0; i < 8; ++i) dp[i] = __shfl_xor(dq[i], 1);
            const int kb = h * 8;
            const int pb = 8 - kb;
            const float* wmy = wsh + kb * HIDDEN + kb;
            const float* wpr = wsh + pb * HIDDEN + kb;
            float o[8];
#pragma unroll
            for (int jj = 0; jj < 8; ++jj) o[jj] = 0.0f;
#pragma unroll
            for (int i = 0; i < 8; ++i) {
#pragma unroll
                for (int jj = 0; jj < 8; ++jj) {
                    o[jj] += dq[i] * wmy[i * HIDDEN + jj];
                    o[jj] += dp[i] * wpr[i * HIDDEN + jj];
                }
            }
            __half hb8[8];
#pragma unroll
            for (int jj = 0; jj < 8; ++jj) hb8[jj] = __float2half(o[jj]);
            *(float4*)(yout + (size_t)grow * HIDDEN + kb) = *(float4*)hb8;
        }
    } else {
        // LAYER 3: @W3 (16x40), my output cols = [h*20, h*20+20)
        float ap[8];
#pragma unroll
        for (int i = 0; i < 8; ++i) ap[i] = __shfl_xor(acc[i], 1);
        const int kb = h * 8;
        const int pb = 8 - kb;
        const int ob = h * 20;
        const float* wmy = wsh + kb * OUT_DIM + ob;
        const float* wpr = wsh + pb * OUT_DIM + ob;
        float o[20];
#pragma unroll
        for (int jj = 0; jj < 20; ++jj) o[jj] = 0.0f;
#pragma unroll
        for (int i = 0; i < 8; ++i) {
#pragma unroll
            for (int jj = 0; jj < 20; ++jj) {
                o[jj] += acc[i] * wmy[i * OUT_DIM + jj];
                o[jj] += ap[i] * wpr[i * OUT_DIM + jj];
            }
        }
        float* orow = out + (size_t)grow * OUT_DIM + ob;
#pragma unroll
        for (int j4 = 0; j4 < 5; ++j4)
            __builtin_nontemporal_store(((const vfloat4*)o)[j4],
                                        (vfloat4*)orow + j4);
    }
}

extern "C" void kernel_launch(void* const* d_in, const int* in_sizes, int n_in,
                              void* d_out, int out_size, void* d_ws,
                              size_t ws_size, hipStream_t stream) {
    const float* feat = (const float*)d_in[0];
    const int* row = (const int*)d_in[1];
    const int* col = (const int*)d_in[2];
    const float* vals = (const float*)d_in[3];
    const float* W1 = (const float*)d_in[4];
    const float* W2 = (const float*)d_in[5];
    const float* W3 = (const float*)d_in[6];
    const float* n1 = (const float*)d_in[7];
    const float* n2 = (const float*)d_in[8];
    const float* n3 = (const float*)d_in[9];
    float* out = (float*)d_out;

    __half* yh1 = (__half*)d_ws;                            // 3.2 MB
    __half* yh2 = yh1 + (size_t)N_NODES * HIDDEN;           // 3.2 MB
    int* cursor = (int*)(yh2 + (size_t)N_NODES * HIDDEN);   // NB ints
    int* rowEnd = cursor + NB;                              // NB*RPB ints
    long long* es = (long long*)(rowEnd + NB * RPB);        // 16.8 MB

    // --- build row-sorted bucketed edge list; overlap sort with layer-1 qd-GEMM
    hipMemsetAsync(cursor, 0, NB * sizeof(int), stream);
    k_bin<<<NBLK_BIN, 256, 0, stream>>>(row, col, vals, cursor, es);
    k_sort_gemm1<<<NB_USED + GEMM1_BLOCKS, 256, 0, stream>>>(
        cursor, es, rowEnd, feat, n1, W1, yh1);

    // Layer 1 spmm + (relu, qd(noise2), @W2) fused epilogue
    k_spmm_f<1><<<NB_USED * 2, 256, 0, stream>>>(rowEnd, es, yh1, n2, W2, yh2,
                                                 nullptr);
    // Layer 2 spmm + (relu, qd(noise3)) fused epilogue
    k_spmm_f<2><<<NB_USED * 2, 256, 0, stream>>>(rowEnd, es, yh2, n3, nullptr,
                                                 yh1, nullptr);
    // Layer 3 spmm + @W3 fused epilogue
    k_spmm_f<3><<<NB_USED * 2, 256, 0, stream>>>(rowEnd, es, yh1, nullptr, W3,
                                                 nullptr, out);
}

// Round 10
// 270.045 us; speedup vs baseline: 1.0789x; 1.0583x over previous
//
#include <hip/hip_runtime.h>
#include <hip/hip_fp16.h>

#define N_NODES 100000
#define N_EDGES 1600000
#define IN_DIM 128
#define HIDDEN 16
#define OUT_DIM 40
#define QMAXF 255.0f

#define NB 512            // row buckets
#define RPB 196           // rows per bucket
#define NB_USED 511       // buckets actually populated (0..510)
#define BUCKET_CAP 4096   // mean fill 3136, 17 sigma headroom
#define TILE 4096         // edges per bin block (R4/R9: 4096 measured best)
#define EPT 16            // edges/thread in k_bin
#define NBLK_BIN ((N_EDGES + TILE - 1) / TILE)  // 391
#define HALF_CAP 2560     // stage cap for 98-row half bucket (mean 1568, 25s)
#define GEMM1_BLOCKS 1537 // 511 + 1537 = 2048

// padded dq buffer: 4 k-blocks of 32 floats, block stride 34 floats
// -> read banks (2*kg+i)%32 distinct across the 4 sixteen-lane groups
#define DQ_STRIDE 34
#define DQ_LEN 136        // 4*34

typedef float vfloat4 __attribute__((ext_vector_type(4)));

__device__ __forceinline__ float qd_one(float x, float noise, float rmin,
                                        float rscale, float inv) {
    float q = rintf((x - rmin) * rscale + noise - 0.5f);
    q = fminf(fmaxf(q, 0.0f), QMAXF);
    return q * inv + rmin;
}

// ---------------- edge binning (once) ---------------------------------------
// [R4-exact form] cursor[] holds per-bucket COUNTS (zeroed via hipMemsetAsync)

__global__ __launch_bounds__(256) void k_bin(
    const int* __restrict__ row, const int* __restrict__ col,
    const float* __restrict__ vals, int* __restrict__ cursor,
    long long* __restrict__ es) {
    __shared__ int hist[NB];
    __shared__ int psum[256];
    __shared__ int lofs[NB];
    __shared__ int lcur[NB];
    __shared__ int gbase[NB];
    __shared__ long long stage[TILE];
    __shared__ int dsti[TILE];

    const int tid = threadIdx.x;
    for (int i = tid; i < NB; i += 256) hist[i] = 0;
    __syncthreads();

    int bk[EPT];
    long long ev[EPT];
    const int e0 = blockIdx.x * TILE;
#pragma unroll
    for (int k = 0; k < EPT; ++k) {
        const int e = e0 + k * 256 + tid;
        if (e < N_EDGES) {
            const int r = __builtin_nontemporal_load(row + e);
            const int cc = __builtin_nontemporal_load(col + e);
            const float vv = __builtin_nontemporal_load(vals + e);
            const int b = r / RPB;
            bk[k] = b;
            const unsigned lo = (unsigned)(cc | ((r - b * RPB) << 17));
            ev[k] = (long long)(((unsigned long long)__float_as_uint(vv) << 32) |
                                lo);
            atomicAdd(&hist[b], 1);
        } else {
            bk[k] = -1;
        }
    }
    __syncthreads();

    const int h0 = hist[2 * tid], h1 = hist[2 * tid + 1];
    psum[tid] = h0 + h1;
    __syncthreads();
    for (int off = 1; off < 256; off <<= 1) {
        int x = (tid >= off) ? psum[tid - off] : 0;
        __syncthreads();
        psum[tid] += x;
        __syncthreads();
    }
    const int excl = (tid == 0) ? 0 : psum[tid - 1];
    lofs[2 * tid] = excl;
    lofs[2 * tid + 1] = excl + h0;
    lcur[2 * tid] = excl;
    lcur[2 * tid + 1] = excl + h0;
    if (h0)
        gbase[2 * tid] = 2 * tid * BUCKET_CAP + atomicAdd(&cursor[2 * tid], h0);
    if (h1)
        gbase[2 * tid + 1] =
            (2 * tid + 1) * BUCKET_CAP + atomicAdd(&cursor[2 * tid + 1], h1);
    __syncthreads();

#pragma unroll
    for (int k = 0; k < EPT; ++k) {
        if (bk[k] >= 0) {
            const int b = bk[k];
            const int lp = atomicAdd(&lcur[b], 1);
            stage[lp] = ev[k];
            dsti[lp] = gbase[b] + (lp - lofs[b]);
        }
    }
    __syncthreads();

    const int S = psum[255];
    for (int i = tid; i < S; i += 256)
        __builtin_nontemporal_store(stage[i], es + dsti[i]);
}

// ---------------- merged: bucket sort (blocks 0..510) + layer1 qd-GEMM ------
// Sort path: R4-exact (direct global scatter, ~3KB LDS).
// gemm1 path: 2 NODES PER WAVE per iteration -> 4 loads in flight (2x MLP),
// two independent reduce/FMA chains sharing w1r (2x ILP). Wave-private padded
// LDS slices, barrier-free.

struct SortLds {
    int hist[256];
    int psum[256];
    int cur[256];
};
union K1Lds {
    SortLds s;
    float dqbuf[4][2][DQ_LEN];  // per-wave, per-node padded slices (4.4KB)
};

__global__ __launch_bounds__(256, 4) void k_sort_gemm1(
    const int* __restrict__ cursor, long long* __restrict__ es,
    int* __restrict__ rowEnd, const float* __restrict__ feat,
    const float* __restrict__ noise, const float* __restrict__ W1,
    __half* __restrict__ y) {
    __shared__ K1Lds u;
    const int tid = threadIdx.x;

    if (blockIdx.x < NB_USED) {
        // ---------- in-register counting sort by row within this bucket -----
        const int b = blockIdx.x;
        const int start = b * BUCKET_CAP;
        const int cnt = cursor[b];

        u.s.hist[tid] = 0;
        __syncthreads();

        long long ev[16];
#pragma unroll
        for (int k = 0; k < 16; ++k) {
            const int i = k * 256 + tid;
            if (i < cnt) {
                ev[k] = es[start + i];
                atomicAdd(&u.s.hist[(int)(((unsigned)ev[k]) >> 17)], 1);
            }
        }
        __syncthreads();  // drains vmcnt: all es reads done before scatter

        u.s.psum[tid] = u.s.hist[tid];
        __syncthreads();
        for (int off = 1; off < 256; off <<= 1) {
            int x = (tid >= off) ? u.s.psum[tid - off] : 0;
            __syncthreads();
            u.s.psum[tid] += x;
            __syncthreads();
        }
        if (tid < RPB) rowEnd[b * RPB + tid] = start + u.s.psum[tid];
        u.s.cur[tid] = u.s.psum[tid] - u.s.hist[tid];
        __syncthreads();

#pragma unroll
        for (int k = 0; k < 16; ++k) {
            const int i = k * 256 + tid;
            if (i < cnt) {
                const int r = (int)(((unsigned)ev[k]) >> 17);
                const int pos = atomicAdd(&u.s.cur[r], 1);
                es[start + pos] = ev[k];
            }
        }
    } else {
        // ---------- layer-1 quant-dequant + GEMM, 2 nodes/wave/iter ---------
        const int vb = blockIdx.x - NB_USED;
        const int lane = tid & 63;
        const int wv = tid >> 6;
        const int col = lane & 15;
        const int kg = lane >> 4;

        float w1r[32];
#pragma unroll
        for (int i = 0; i < 32; ++i) w1r[i] = W1[(kg * 32 + i) * HIDDEN + col];

        float* const sl0 = u.dqbuf[wv][0];
        float* const sl1 = u.dqbuf[wv][1];
        float2* const wp0 = (float2*)&sl0[kg * DQ_STRIDE + (lane & 15) * 2];
        float2* const wp1 = (float2*)&sl1[kg * DQ_STRIDE + (lane & 15) * 2];
        const float* const dqk0 = &sl0[kg * DQ_STRIDE];
        const float* const dqk1 = &sl1[kg * DQ_STRIDE];

        const int ngroups = N_NODES / 8;  // 12500 (8 nodes per block-iter)
        for (int g = vb; g < ngroups; g += GEMM1_BLOCKS) {
            const int node0 = g * 8 + wv * 2;
            const int node1 = node0 + 1;
            // 4 independent loads in flight before any dependent compute
            const unsigned long long xr0 = __builtin_nontemporal_load(
                (const unsigned long long*)(feat + (size_t)node0 * IN_DIM) +
                lane);
            const unsigned long long nr0 = __builtin_nontemporal_load(
                (const unsigned long long*)(noise + (size_t)node0 * IN_DIM) +
                lane);
            const unsigned long long xr1 = __builtin_nontemporal_load(
                (const unsigned long long*)(feat + (size_t)node1 * IN_DIM) +
                lane);
            const unsigned long long nr1 = __builtin_nontemporal_load(
                (const unsigned long long*)(noise + (size_t)node1 * IN_DIM) +
                lane);

            const float xx0 = __uint_as_float((unsigned)xr0);
            const float xy0 = __uint_as_float((unsigned)(xr0 >> 32));
            const float nx0 = __uint_as_float((unsigned)nr0);
            const float ny0 = __uint_as_float((unsigned)(nr0 >> 32));
            const float xx1 = __uint_as_float((unsigned)xr1);
            const float xy1 = __uint_as_float((unsigned)(xr1 >> 32));
            const float nx1 = __uint_as_float((unsigned)nr1);
            const float ny1 = __uint_as_float((unsigned)(nr1 >> 32));

            float m0 = fminf(xx0, xy0), M0 = fmaxf(xx0, xy0);
            float m1 = fminf(xx1, xy1), M1 = fmaxf(xx1, xy1);
#pragma unroll
            for (int off = 1; off < 64; off <<= 1) {
                m0 = fminf(m0, __shfl_xor(m0, off));
                M0 = fmaxf(M0, __shfl_xor(M0, off));
                m1 = fminf(m1, __shfl_xor(m1, off));
                M1 = fmaxf(M1, __shfl_xor(M1, off));
            }
            const float rs0 = QMAXF / (M0 - m0);
            const float iv0 = (M0 - m0) / QMAXF;
            const float rs1 = QMAXF / (M1 - m1);
            const float iv1 = (M1 - m1) / QMAXF;
            float2 dq0, dq1;
            dq0.x = qd_one(xx0, nx0, m0, rs0, iv0);
            dq0.y = qd_one(xy0, ny0, m0, rs0, iv0);
            dq1.x = qd_one(xx1, nx1, m1, rs1, iv1);
            dq1.y = qd_one(xy1, ny1, m1, rs1, iv1);
            *wp0 = dq0;
            *wp1 = dq1;
            float a0 = 0.0f, a1 = 0.0f;
#pragma unroll
            for (int i = 0; i < 32; ++i) {
                a0 += dqk0[i] * w1r[i];
                a1 += dqk1[i] * w1r[i];
            }
            a0 += __shfl_xor(a0, 16);
            a0 += __shfl_xor(a0, 32);
            a1 += __shfl_xor(a1, 16);
            a1 += __shfl_xor(a1, 32);
            if (lane < 16) {
                y[(size_t)node0 * HIDDEN + lane] = __float2half(a0);
                y[(size_t)node1 * HIDDEN + lane] = __float2half(a1);
            }
        }
    }
}

// ---------------- SpMM with fused per-layer epilogue ------------------------
// [R4-exact form: LDS edge stage + 4-wide unrolled gather]
// LAYER==1: spmm -> relu -> qd(noise2) -> @W2 -> half yout
// LAYER==2: spmm -> relu -> qd(noise3) -> half yout
// LAYER==3: spmm -> @W3 -> float out

template <int LAYER>
__global__ __launch_bounds__(256, 4) void k_spmm_f(
    const int* __restrict__ rowEnd, const long long* __restrict__ es,
    const __half* __restrict__ y, const float* __restrict__ noise,
    const float* __restrict__ W, __half* __restrict__ yout,
    float* __restrict__ out) {
    __shared__ long long stage[HALF_CAP];  // 20.5 KB
    __shared__ int rp[100];
    __shared__ int sh_se[2];
    __shared__ float wsh[LAYER == 1 ? (HIDDEN * HIDDEN)
                                    : (LAYER == 3 ? (HIDDEN * OUT_DIM) : 4)];

    const int b = blockIdx.x >> 1;
    const int hbk = blockIdx.x & 1;
    const int tid = threadIdx.x;
    const int r0 = hbk * 98;
    const int gb = b * RPB;
    const int bstart = b * BUCKET_CAP;

    if (tid == 0) {
        sh_se[0] = (r0 == 0) ? bstart : rowEnd[gb + r0 - 1];
        sh_se[1] = rowEnd[gb + r0 + 97];
    }
    if (tid < 99) rp[tid + 1] = rowEnd[gb + r0 + tid];
    if (LAYER == 1) {
        wsh[tid] = W[tid];  // 256 weights, 256 threads
    }
    if (LAYER == 3) {
        for (int i = tid; i < HIDDEN * OUT_DIM; i += 256) wsh[i] = W[i];
    }
    __syncthreads();
    const int estart = sh_se[0];
    const int cnt = sh_se[1] - estart;
    if (tid == 0) rp[0] = estart;
    __syncthreads();

    for (int i = tid; i < cnt; i += 256)
        stage[i] = __builtin_nontemporal_load(es + estart + i);
    __syncthreads();

    if (tid >= 196) return;
    const int lr = tid >> 1;  // 0..97 local row
    const int h = tid & 1;    // half-row: halfs [h*8, h*8+8)
    const int grow = gb + r0 + lr;
    int j = rp[lr] - estart;
    const int je = rp[lr + 1] - estart;

    float acc[8];
#pragma unroll
    for (int i = 0; i < 8; ++i) acc[i] = 0.0f;

    for (; j + 4 <= je; j += 4) {
        const long long e0 = stage[j], e1 = stage[j + 1];
        const long long e2 = stage[j + 2], e3 = stage[j + 3];
        const uint4 a0 = *(const uint4*)(y + (size_t)(((unsigned)e0) & 0x1FFFF) * HIDDEN + h * 8);
        const uint4 a1 = *(const uint4*)(y + (size_t)(((unsigned)e1) & 0x1FFFF) * HIDDEN + h * 8);
        const uint4 a2 = *(const uint4*)(y + (size_t)(((unsigned)e2) & 0x1FFFF) * HIDDEN + h * 8);
        const uint4 a3 = *(const uint4*)(y + (size_t)(((unsigned)e3) & 0x1FFFF) * HIDDEN + h * 8);
        const float v0 = __uint_as_float((unsigned)((unsigned long long)e0 >> 32));
        const float v1 = __uint_as_float((unsigned)((unsigned long long)e1 >> 32));
        const float v2 = __uint_as_float((unsigned)((unsigned long long)e2 >> 32));
        const float v3 = __uint_as_float((unsigned)((unsigned long long)e3 >> 32));
        const unsigned* p0 = (const unsigned*)&a0;
        const unsigned* p1 = (const unsigned*)&a1;
        const unsigned* p2 = (const unsigned*)&a2;
        const unsigned* p3 = (const unsigned*)&a3;
#pragma unroll
        for (int q = 0; q < 4; ++q) {
            float2 f;
            f = __half22float2(*(const __half2*)&p0[q]);
            acc[2 * q] += v0 * f.x; acc[2 * q + 1] += v0 * f.y;
            f = __half22float2(*(const __half2*)&p1[q]);
            acc[2 * q] += v1 * f.x; acc[2 * q + 1] += v1 * f.y;
            f = __half22float2(*(const __half2*)&p2[q]);
            acc[2 * q] += v2 * f.x; acc[2 * q + 1] += v2 * f.y;
            f = __half22float2(*(const __half2*)&p3[q]);
            acc[2 * q] += v3 * f.x; acc[2 * q + 1] += v3 * f.y;
        }
    }
    for (; j < je; ++j) {
        const long long e = stage[j];
        const float v = __uint_as_float((unsigned)((unsigned long long)e >> 32));
        const uint4 a = *(const uint4*)(y + (size_t)(((unsigned)e) & 0x1FFFF) * HIDDEN + h * 8);
        const unsigned* p = (const unsigned*)&a;
#pragma unroll
        for (int q = 0; q < 4; ++q) {
            const float2 f = __half22float2(*(const __half2*)&p[q]);
            acc[2 * q] += v * f.x;
            acc[2 * q + 1] += v * f.y;
        }
    }

    if (grow >= N_NODES) return;

    if (LAYER == 1 || LAYER == 2) {
        // relu + row min/max (exchange with partner half)
#pragma unroll
        for (int i = 0; i < 8; ++i) acc[i] = fmaxf(acc[i], 0.0f);
        float m = acc[0], M = acc[0];
#pragma unroll
        for (int i = 1; i < 8; ++i) {
            m = fminf(m, acc[i]);
            M = fmaxf(M, acc[i]);
        }
        m = fminf(m, __shfl_xor(m, 1));
        M = fmaxf(M, __shfl_xor(M, 1));
        const float rscale = QMAXF / (M - m);
        const float inv = (M - m) / QMAXF;
        float nz[8];
        {
            const float4* nr =
                (const float4*)(noise + (size_t)grow * HIDDEN + h * 8);
            ((float4*)nz)[0] = nr[0];
            ((float4*)nz)[1] = nr[1];
        }
        float dq[8];
#pragma unroll
        for (int i = 0; i < 8; ++i)
            dq[i] = qd_one(acc[i], nz[i], m, rscale, inv);

        if (LAYER == 2) {
            __half hb8[8];
#pragma unroll
            for (int i = 0; i < 8; ++i) hb8[i] = __float2half(dq[i]);
            *(float4*)(yout + (size_t)grow * HIDDEN + h * 8) = *(float4*)hb8;
        } else {
            // @W2: my k-rows = [h*8, h*8+8), partner's via shuffle; my output
            // cols = [h*8, h*8+8).
            float dp[8];
#pragma unroll
            for (int i = 0; i < 8; ++i) dp[i] = __shfl_xor(dq[i], 1);
            const int kb = h * 8;
            const int pb = 8 - kb;
            const float* wmy = wsh + kb * HIDDEN + kb;
            const float* wpr = wsh + pb * HIDDEN + kb;
            float o[8];
#pragma unroll
            for (int jj = 0; jj < 8; ++jj) o[jj] = 0.0f;
#pragma unroll
            for (int i = 0; i < 8; ++i) {
#pragma unroll
                for (int jj = 0; jj < 8; ++jj) {
                    o[jj] += dq[i] * wmy[i * HIDDEN + jj];
                    o[jj] += dp[i] * wpr[i * HIDDEN + jj];
                }
            }
            __half hb8[8];
#pragma unroll
            for (int jj = 0; jj < 8; ++jj) hb8[jj] = __float2half(o[jj]);
            *(float4*)(yout + (size_t)grow * HIDDEN + kb) = *(float4*)hb8;
        }
    } else {
        // LAYER 3: @W3 (16x40), my output cols = [h*20, h*20+20)
        float ap[8];
#pragma unroll
        for (int i = 0; i < 8; ++i) ap[i] = __shfl_xor(acc[i], 1);
        const int kb = h * 8;
        const int pb = 8 - kb;
        const int ob = h * 20;
        const float* wmy = wsh + kb * OUT_DIM + ob;
        const float* wpr = wsh + pb * OUT_DIM + ob;
        float o[20];
#pragma unroll
        for (int jj = 0; jj < 20; ++jj) o[jj] = 0.0f;
#pragma unroll
        for (int i = 0; i < 8; ++i) {
#pragma unroll
            for (int jj = 0; jj < 20; ++jj) {
                o[jj] += acc[i] * wmy[i * OUT_DIM + jj];
                o[jj] += ap[i] * wpr[i * OUT_DIM + jj];
            }
        }
        float* orow = out + (size_t)grow * OUT_DIM + ob;
#pragma unroll
        for (int j4 = 0; j4 < 5; ++j4)
            __builtin_nontemporal_store(((const vfloat4*)o)[j4],
                                        (vfloat4*)orow + j4);
    }
}

extern "C" void kernel_launch(void* const* d_in, const int* in_sizes, int n_in,
                              void* d_out, int out_size, void* d_ws,
                              size_t ws_size, hipStream_t stream) {
    const float* feat = (const float*)d_in[0];
    const int* row = (const int*)d_in[1];
    const int* col = (const int*)d_in[2];
    const float* vals = (const float*)d_in[3];
    const float* W1 = (const float*)d_in[4];
    const float* W2 = (const float*)d_in[5];
    const float* W3 = (const float*)d_in[6];
    const float* n1 = (const float*)d_in[7];
    const float* n2 = (const float*)d_in[8];
    const float* n3 = (const float*)d_in[9];
    float* out = (float*)d_out;

    __half* yh1 = (__half*)d_ws;                            // 3.2 MB
    __half* yh2 = yh1 + (size_t)N_NODES * HIDDEN;           // 3.2 MB
    int* cursor = (int*)(yh2 + (size_t)N_NODES * HIDDEN);   // NB ints
    int* rowEnd = cursor + NB;                              // NB*RPB ints
    long long* es = (long long*)(rowEnd + NB * RPB);        // 16.8 MB

    // --- build row-sorted bucketed edge list; overlap sort with layer-1 qd-GEMM
    hipMemsetAsync(cursor, 0, NB * sizeof(int), stream);
    k_bin<<<NBLK_BIN, 256, 0, stream>>>(row, col, vals, cursor, es);
    k_sort_gemm1<<<NB_USED + GEMM1_BLOCKS, 256, 0, stream>>>(
        cursor, es, rowEnd, feat, n1, W1, yh1);

    // Layer 1 spmm + (relu, qd(noise2), @W2) fused epilogue
    k_spmm_f<1><<<NB_USED * 2, 256, 0, stream>>>(rowEnd, es, yh1, n2, W2, yh2,
                                                 nullptr);
    // Layer 2 spmm + (relu, qd(noise3)) fused epilogue
    k_spmm_f<2><<<NB_USED * 2, 256, 0, stream>>>(rowEnd, es, yh2, n3, nullptr,
                                                 yh1, nullptr);
    // Layer 3 spmm + @W3 fused epilogue
    k_spmm_f<3><<<NB_USED * 2, 256, 0, stream>>>(rowEnd, es, yh1, nullptr, W3,
                                                 nullptr, out);
}